// Round 4
// baseline (488.086 us; speedup 1.0000x reference)
//
#include <hip/hip_runtime.h>
#include <hip/hip_cooperative_groups.h>

namespace cg = cooperative_groups;

typedef unsigned short u16;
typedef unsigned int   u32;
typedef __attribute__((ext_vector_type(8))) short bf16x8;   // 8 bf16 in 4 VGPRs
typedef __attribute__((ext_vector_type(4))) float f32x4;

#define KCAT 5376   // 6*768 (mean) + 768 (root)

struct Params {
    const float* embed; const int* labels;
    const float* c1w; const float* c1root; const float* c1b;
    const float* c2w; const float* c2root; const float* c2b;
    const float* cw1; const float* cb1; const float* cw2;
    const float* cb2; const float* cw3; const float* cb3;
    u16* S; float* recip; u16* Acat1; u16* Acat2;
    u16* Pemb; u16* Px; u16* PW1; u16* PC1; u16* Pw2c; u16* Pw3;
    u16* W2C1p; float* cvec; float* AB; float* outp;
};

__device__ inline u16 f2bf(float f) {
    union { float f; u32 u; } v; v.f = f;
    u32 r = v.u + 0x7FFFu + ((v.u >> 16) & 1u);   // RNE
    return (u16)(r >> 16);
}
__device__ inline f32x4 mfma16(bf16x8 a, bf16x8 b, f32x4 c) {
    return __builtin_amdgcn_mfma_f32_16x16x32_bf16(a, b, c, 0, 0, 0);
}

// pack one 32x16 tile of a row-major f32 matrix into MFMA B-fragment layout (bf16)
__device__ inline void pack_f32(const float* __restrict__ src, int ld, int rows, int cols,
                                u16* __restrict__ dst, int ntot, int kt0, int nt0,
                                int ntiles, int tile) {
    int ktile = tile / ntiles, ntile = tile % ntiles;
    int lane = threadIdx.x & 63;
    int m = lane & 15, hi = lane >> 4;
    int n = ntile * 16 + m;
    u16 tmp[8];
#pragma unroll
    for (int j = 0; j < 8; ++j) {
        int kk = ktile * 32 + hi * 8 + j;
        tmp[j] = (kk < rows && n < cols) ? f2bf(src[(size_t)kk * ld + n]) : (u16)0;
    }
    u16* d = dst + (((size_t)(kt0 + ktile) * ntot + (nt0 + ntile)) * 64 + lane) * 8;
    *(bf16x8*)d = *(const bf16x8*)tmp;
}

// one-wave 16x16 GEMM tile, A row-major bf16, B pre-packed
__device__ inline f32x4 gemm_tile(const u16* __restrict__ A, int lda,
                                  const u16* __restrict__ Bp,
                                  int row0, int nt, int ntot, int ktiles) {
    int lane = threadIdx.x & 63;
    int m = lane & 15, hi = lane >> 4;
    const u16* arow = A + (size_t)(row0 + m) * lda + hi * 8;
    const u16* bptr = Bp + ((size_t)nt * 64 + lane) * 8;
    f32x4 acc = {0.f, 0.f, 0.f, 0.f};
#pragma unroll 4
    for (int kt = 0; kt < ktiles; ++kt) {
        bf16x8 a = *(const bf16x8*)(arow + kt * 32);
        bf16x8 b = *(const bf16x8*)(bptr + (size_t)kt * ntot * 512);
        acc = mfma16(a, b, acc);
    }
    return acc;
}

// ---------------- P0: S/recip + embed tail + all packs + cvec ----------------
__device__ void phase0(const Params& p) {
    int w = threadIdx.x >> 6, lane = threadIdx.x & 63;
    int nw = gridDim.x * 4;
    for (int job = blockIdx.x * 4 + w; job < 9628; job += nw) {
        if (job < 256) {
            int k = job;
            int lab[4];
#pragma unroll
            for (int g = 0; g < 4; ++g) {
                int i = lane + g * 64;
                lab[g] = (i == k) ? -1 : p.labels[i * 255 + k - (k > i ? 1 : 0)];
            }
#pragma unroll
            for (int r = 0; r < 6; ++r) {
                int c = 0;
#pragma unroll
                for (int g = 0; g < 4; ++g) c += __popcll(__ballot(lab[g] == r));
#pragma unroll
                for (int g = 0; g < 4; ++g) {
                    int i = lane + g * 64;
                    p.S[(k * 6 + r) * 256 + i] = (lab[g] == r) ? (u16)0x3F80 : (u16)0;
                }
                if (lane == 0) p.recip[k * 6 + r] = 1.0f / (float)(c > 1 ? c : 1);
            }
        } else if (job < 640) {
            int idx = (job - 256) * 512 + lane * 8;
            int row = idx / 768, col = idx - row * 768;
            f32x4 a = *(const f32x4*)(p.embed + idx);
            f32x4 b = *(const f32x4*)(p.embed + idx + 4);
            u16 tmp[8];
#pragma unroll
            for (int e = 0; e < 4; ++e) { tmp[e] = f2bf(a[e]); tmp[e + 4] = f2bf(b[e]); }
            *(bf16x8*)(p.Acat1 + (size_t)row * KCAT + 4608 + col) = *(const bf16x8*)tmp;
        }
        else if (job < 1024) pack_f32(p.embed, 768, 256, 768, p.Pemb, 48, 0, 0, 48, job - 640);
        else if (job < 7936) pack_f32(p.c1w, 768, 4608, 768, p.PW1, 48, 0, 0, 48, job - 1024);
        else if (job < 9088) pack_f32(p.c1root, 768, 768, 768, p.PW1, 48, 144, 0, 48, job - 7936);
        else if (job < 9328) pack_f32(p.cw1, 150, 768, 150, p.PC1, 20, 0, 0, 10, job - 9088);
        else if (job < 9568) pack_f32(p.cw1 + 768 * 150, 150, 768, 150, p.PC1, 20, 0, 10, 10, job - 9328);
        else if (job < 9618) pack_f32(p.cw2, 150, 150, 150, p.Pw2c, 10, 0, 0, 10, job - 9568);
        else if (job < 9623) pack_f32(p.cw3, 7, 150, 7, p.Pw3, 1, 0, 0, 1, job - 9618);
        else {
            // cvec[j] = c2b @ C1cat[:,j] (+ b1[j] on the A-half); 320 lanes over 5 wave-jobs
            int j = (job - 9623) * 64 + lane;
            float s = 0.f;
            const float* col;
            bool valid;
            if (j < 160) { valid = (j < 150); col = p.cw1 + j; }
            else         { int q = j - 160; valid = (q < 150); col = p.cw1 + (size_t)768 * 150 + q; }
            if (valid) {
                float acc = 0.f;
                for (int d = 0; d < 768; ++d) acc = fmaf(p.c2b[d], col[(size_t)d * 150], acc);
                s = acc + ((j < 150) ? p.cb1[j] : 0.f);
            }
            p.cvec[j] = s;
        }
    }
}

// ---------------- mean tile: (S @ Bp) * recip -> Acat ----------------
__device__ void mean_tile(const Params& p, const u16* Bp, u16* Acat, int tile) {
    int rt = tile / 48, nt = tile % 48;
    f32x4 acc = gemm_tile(p.S, 256, Bp, rt * 16, nt, 48, 8);
    int lane = threadIdx.x & 63;
    int col = nt * 16 + (lane & 15), hi = lane >> 4;
#pragma unroll
    for (int r = 0; r < 4; ++r) {
        int g = rt * 16 + hi * 4 + r;
        float scale = p.recip[g];
        int node = g / 6, rel = g - node * 6;
        Acat[(size_t)node * KCAT + rel * 768 + col] = f2bf(acc[r] * scale);
    }
}

// ---------------- W2C1 = Wcat2 @ C1cat, output packed as B-fragments -----------
// per wave-job: 32 rows x 64 cols (2 m-frags x 4 n-tiles), K=768
__device__ void w2c1_job(const Params& p, int q) {
    int lane = threadIdx.x & 63;
    int mtb = q / 5, ntb = q % 5;
    int m = lane & 15, hi = lane >> 4;
    int row0 = mtb * 32;
    f32x4 acc[2][4];
#pragma unroll
    for (int t = 0; t < 2; ++t)
#pragma unroll
        for (int qq = 0; qq < 4; ++qq) acc[t][qq] = {0.f, 0.f, 0.f, 0.f};
    for (int kt = 0; kt < 24; ++kt) {
        int e0 = kt * 32 + hi * 8;
        bf16x8 a[2];
#pragma unroll
        for (int t = 0; t < 2; ++t) {
            int r = row0 + t * 16 + m;
            const float* src = (r < 4608) ? (p.c2w + (size_t)r * 768)
                                          : (p.c2root + (size_t)(r - 4608) * 768);
            f32x4 x0 = *(const f32x4*)(src + e0);
            f32x4 x1 = *(const f32x4*)(src + e0 + 4);
            u16 tmp[8];
#pragma unroll
            for (int e = 0; e < 4; ++e) { tmp[e] = f2bf(x0[e]); tmp[e + 4] = f2bf(x1[e]); }
            a[t] = *(const bf16x8*)tmp;
        }
#pragma unroll
        for (int qq = 0; qq < 4; ++qq) {
            int nt = ntb * 4 + qq;
            bf16x8 b = *(const bf16x8*)(p.PC1 + ((size_t)(kt * 20 + nt) * 64 + lane) * 8);
            acc[0][qq] = mfma16(a[0], b, acc[0][qq]);
            acc[1][qq] = mfma16(a[1], b, acc[1][qq]);
        }
    }
#pragma unroll
    for (int t = 0; t < 2; ++t)
#pragma unroll
        for (int qq = 0; qq < 4; ++qq) {
            int nt = ntb * 4 + qq;
#pragma unroll
            for (int r4 = 0; r4 < 4; ++r4) {
                int kg = row0 + t * 16 + hi * 4 + r4;
                int kt2 = kg >> 5, j = kg & 7, hi2 = (kg >> 3) & 3;
                p.W2C1p[(((size_t)kt2 * 20 + nt) * 64 + hi2 * 16 + m) * 8 + j] = f2bf(acc[t][qq][r4]);
            }
        }
}

__device__ void phase1(const Params& p) {
    int w = threadIdx.x >> 6;
    int nw = gridDim.x * 4;
    for (int job = blockIdx.x * 4 + w; job < 5448; job += nw) {
        if (job < 4608) mean_tile(p, p.Pemb, p.Acat1, job);
        else            w2c1_job(p, job - 4608);
    }
}

// ---------------- P2: conv1 = Acat1 @ Wcat1 (K split over 4 waves, LDS reduce) --
__device__ void phase2(const Params& p) {
    __shared__ float red[4 * 64 * 4];
    int w = threadIdx.x >> 6, lane = threadIdx.x & 63;
    int m = lane & 15, hi = lane >> 4;
    for (int b = blockIdx.x; b < 768; b += gridDim.x) {
        int rt = b / 48, nt = b % 48;
        const u16* arow = p.Acat1 + (size_t)(rt * 16 + m) * KCAT + hi * 8;
        const u16* bptr = p.PW1 + ((size_t)nt * 64 + lane) * 8;
        f32x4 acc = {0.f, 0.f, 0.f, 0.f};
#pragma unroll 4
        for (int kt = w * 42; kt < (w + 1) * 42; ++kt) {
            bf16x8 a = *(const bf16x8*)(arow + kt * 32);
            bf16x8 bb = *(const bf16x8*)(bptr + (size_t)kt * 48 * 512);
            acc = mfma16(a, bb, acc);
        }
        *(f32x4*)&red[(w * 64 + lane) * 4] = acc;
        __syncthreads();
        if (w == 0) {
            f32x4 s = *(f32x4*)&red[lane * 4];
#pragma unroll
            for (int ww = 1; ww < 4; ++ww) s += *(f32x4*)&red[(ww * 64 + lane) * 4];
            int col = nt * 16 + m;
            float bbv = p.c1b[col];
#pragma unroll
            for (int r = 0; r < 4; ++r) {
                int g = rt * 16 + hi * 4 + r;
                float v = fmaxf(s[r] + bbv, 0.f);
                u16 bv = f2bf(v);
                p.Acat2[(size_t)g * KCAT + 4608 + col] = bv;
                p.Px[(((size_t)(g >> 5) * 48 + nt) * 64 + (((g >> 3) & 3) * 16 + m)) * 8 + (g & 7)] = bv;
            }
        }
        __syncthreads();
    }
}

__device__ void phase3(const Params& p) {
    int w = threadIdx.x >> 6;
    int nw = gridDim.x * 4;
    for (int job = blockIdx.x * 4 + w; job < 4608; job += nw)
        mean_tile(p, p.Px, p.Acat2, job);
}

// ---------------- P4: AB = Acat2 @ W2C1p + cvec (K split over 4 waves) ---------
__device__ void phase4(const Params& p) {
    __shared__ float red2[4 * 64 * 4];
    int w = threadIdx.x >> 6, lane = threadIdx.x & 63;
    int m = lane & 15, hi = lane >> 4;
    for (int b = blockIdx.x; b < 320; b += gridDim.x) {
        int rt = b / 20, nt = b % 20;
        const u16* arow = p.Acat2 + (size_t)(rt * 16 + m) * KCAT + hi * 8;
        const u16* bptr = p.W2C1p + ((size_t)nt * 64 + lane) * 8;
        f32x4 acc = {0.f, 0.f, 0.f, 0.f};
#pragma unroll 4
        for (int kt = w * 42; kt < (w + 1) * 42; ++kt) {
            bf16x8 a = *(const bf16x8*)(arow + kt * 32);
            bf16x8 bb = *(const bf16x8*)(bptr + (size_t)kt * 20 * 512);
            acc = mfma16(a, bb, acc);
        }
        *(f32x4*)&red2[(w * 64 + lane) * 4] = acc;
        __syncthreads();
        if (w == 0) {
            f32x4 s = *(f32x4*)&red2[lane * 4];
#pragma unroll
            for (int ww = 1; ww < 4; ++ww) s += *(f32x4*)&red2[(ww * 64 + lane) * 4];
            int j = nt * 16 + m;
            float cv = p.cvec[j];
#pragma unroll
            for (int r = 0; r < 4; ++r) {
                int g = rt * 16 + hi * 4 + r;
                p.AB[(size_t)g * 320 + j] = s[r] + cv;
            }
        }
        __syncthreads();
    }
}

// ---------------- P5: fused pair MLP ----------------
__device__ void phase5(const Params& p) {
    __shared__ u16 h2t[4][16][168];
    int w = threadIdx.x >> 6, lane = threadIdx.x & 63;
    int m = lane & 15, hi = lane >> 4;
    for (int job = blockIdx.x; job < 1020; job += gridDim.x) {
        int pb = job * 64 + w * 16;
        int pp = pb + m;
        int i = pp / 255, rem = pp - i * 255;
        int k = rem + (rem >= i ? 1 : 0);
        const float* Ar = p.AB + (size_t)i * 320;
        const float* Br = p.AB + (size_t)k * 320 + 160;

        bf16x8 af[5];
#pragma unroll
        for (int kk = 0; kk < 5; ++kk) {
            int c = kk * 32 + hi * 8;
            f32x4 a0 = *(const f32x4*)(Ar + c);
            f32x4 a1 = *(const f32x4*)(Ar + c + 4);
            f32x4 b0 = *(const f32x4*)(Br + c);
            f32x4 b1v = *(const f32x4*)(Br + c + 4);
            f32x4 s0 = a0 + b0, s1 = a1 + b1v;
            bf16x8 f;
#pragma unroll
            for (int e = 0; e < 4; ++e) {
                f[e]     = (short)f2bf(fmaxf(s0[e], 0.f));
                f[e + 4] = (short)f2bf(fmaxf(s1[e], 0.f));
            }
            af[kk] = f;
        }

#pragma unroll
        for (int nt = 0; nt < 10; ++nt) {
            f32x4 acc = {0.f, 0.f, 0.f, 0.f};
#pragma unroll
            for (int kk = 0; kk < 5; ++kk) {
                bf16x8 b = *(const bf16x8*)(p.Pw2c + ((size_t)(kk * 10 + nt) * 64 + lane) * 8);
                acc = mfma16(af[kk], b, acc);
            }
            int col = nt * 16 + m;
            float bb = (col < 150) ? p.cb2[col] : 0.f;
#pragma unroll
            for (int r = 0; r < 4; ++r) {
                float v = fmaxf(acc[r] + bb, 0.f);
                h2t[w][hi * 4 + r][col] = f2bf(v);
            }
        }
        __syncthreads();

        f32x4 acc3 = {0.f, 0.f, 0.f, 0.f};
#pragma unroll
        for (int kk = 0; kk < 5; ++kk) {
            bf16x8 a = *(const bf16x8*)(&h2t[w][m][kk * 32 + hi * 8]);
            bf16x8 b = *(const bf16x8*)(p.Pw3 + ((size_t)kk * 64 + lane) * 8);
            acc3 = mfma16(a, b, acc3);
        }
        if (m < 7) {
            float bb = p.cb3[m];
#pragma unroll
            for (int r = 0; r < 4; ++r) {
                int p2 = pb + hi * 4 + r;
                p.outp[p2 * 7 + m] = acc3[r] + bb;
            }
        }
        __syncthreads();
    }
}

__global__ __launch_bounds__(256, 4) void kfused(Params p) {
    cg::grid_group g = cg::this_grid();
    phase0(p); g.sync();
    phase1(p); g.sync();
    phase2(p); g.sync();
    phase3(p); g.sync();
    phase4(p); g.sync();
    phase5(p);
}

// fallback wrappers (plain launches, used only if cooperative launch is rejected)
__global__ __launch_bounds__(256) void kp0(Params p) { phase0(p); }
__global__ __launch_bounds__(256) void kp1(Params p) { phase1(p); }
__global__ __launch_bounds__(256) void kp2(Params p) { phase2(p); }
__global__ __launch_bounds__(256) void kp3(Params p) { phase3(p); }
__global__ __launch_bounds__(256) void kp4(Params p) { phase4(p); }
__global__ __launch_bounds__(256) void kp5(Params p) { phase5(p); }

extern "C" void kernel_launch(void* const* d_in, const int* in_sizes, int n_in,
                              void* d_out, int out_size, void* d_ws, size_t ws_size,
                              hipStream_t stream) {
    char* ws = (char*)d_ws;
    Params hp;
    hp.embed  = (const float*)d_in[0];
    hp.labels = (const int*)d_in[1];
    hp.c1w    = (const float*)d_in[2];
    hp.c1root = (const float*)d_in[3];
    hp.c1b    = (const float*)d_in[4];
    hp.c2w    = (const float*)d_in[5];
    hp.c2root = (const float*)d_in[6];
    hp.c2b    = (const float*)d_in[7];
    // d_in[8..13] (base_*) are dead code
    hp.cw1    = (const float*)d_in[14];
    hp.cb1    = (const float*)d_in[15];
    hp.cw2    = (const float*)d_in[16];
    hp.cb2    = (const float*)d_in[17];
    hp.cw3    = (const float*)d_in[18];
    hp.cb3    = (const float*)d_in[19];
    hp.S      = (u16*)(ws + 0);            // 786432
    hp.recip  = (float*)(ws + 786432);     // 6144
    hp.Acat1  = (u16*)(ws + 792576);       // 2752512
    hp.Acat2  = (u16*)(ws + 3545088);      // 2752512
    hp.Pemb   = (u16*)(ws + 6297600);      // 393216
    hp.Px     = (u16*)(ws + 6690816);      // 393216
    hp.PW1    = (u16*)(ws + 7084032);      // 8257536
    hp.PC1    = (u16*)(ws + 15341568);     // 491520
    hp.Pw2c   = (u16*)(ws + 15833088);     // 102400
    hp.Pw3    = (u16*)(ws + 15935488);     // 10240
    hp.W2C1p  = (u16*)(ws + 15945728);     // 3440640
    hp.cvec   = (float*)(ws + 19386368);   // 1280
    hp.AB     = (float*)(ws + 19387648);   // 327680
    hp.outp   = (float*)d_out;

    int maxb = 0;
    hipError_t qe = hipOccupancyMaxActiveBlocksPerMultiprocessor(
        &maxb, reinterpret_cast<const void*>(&kfused), 256, 0);
    int grid = (qe == hipSuccess && maxb > 0) ? maxb * 256 : 0;   // 256 CUs on MI355X
    if (grid > 1024) grid = 1024;
    hipError_t le = hipErrorUnknown;
    if (grid >= 64) {
        void* args[] = { (void*)&hp };
        le = hipLaunchCooperativeKernel(reinterpret_cast<const void*>(&kfused),
                                        dim3(grid), dim3(256), args, 0, stream);
    }
    if (le != hipSuccess) {
        kp0<<<2407, 256, 0, stream>>>(hp);
        kp1<<<1362, 256, 0, stream>>>(hp);
        kp2<<<768, 256, 0, stream>>>(hp);
        kp3<<<1152, 256, 0, stream>>>(hp);
        kp4<<<320, 256, 0, stream>>>(hp);
        kp5<<<1020, 256, 0, stream>>>(hp);
    }
}

// Round 6
// 139.355 us; speedup vs baseline: 3.5025x; 3.5025x over previous
//
#include <hip/hip_runtime.h>

typedef unsigned short u16;
typedef unsigned int   u32;
typedef __attribute__((ext_vector_type(8))) short bf16x8;   // 8 bf16 in 4 VGPRs
typedef __attribute__((ext_vector_type(4))) float f32x4;

#define KCAT 5376   // 6*768 (mean) + 768 (root)

struct Params {
    const float* embed; const int* labels;
    const float* c1w; const float* c1root; const float* c1b;
    const float* c2w; const float* c2root; const float* c2b;
    const float* cw1; const float* cb1; const float* cw2;
    const float* cb2; const float* cw3; const float* cb3;
    u16* S; float* recip; u16* Acat1; u16* Acat2;
    u16* Pemb; u16* Px; u16* PW1; u16* PC1; u16* Pw2c; u16* Pw3;
    u16* W2C1p; float* cvec; float* AB; float* outp;
};

__device__ inline u16 f2bf(float f) {
    union { float f; u32 u; } v; v.f = f;
    u32 r = v.u + 0x7FFFu + ((v.u >> 16) & 1u);   // RNE
    return (u16)(r >> 16);
}
__device__ inline f32x4 mfma16(bf16x8 a, bf16x8 b, f32x4 c) {
    return __builtin_amdgcn_mfma_f32_16x16x32_bf16(a, b, c, 0, 0, 0);
}

// pack one 32x16 tile of a row-major f32 matrix into MFMA B-fragment layout (bf16)
__device__ inline void pack_f32(const float* __restrict__ src, int ld, int rows, int cols,
                                u16* __restrict__ dst, int ntot, int kt0, int nt0,
                                int ntiles, int tile) {
    int ktile = tile / ntiles, ntile = tile % ntiles;
    int lane = threadIdx.x & 63;
    int m = lane & 15, hi = lane >> 4;
    int n = ntile * 16 + m;
    u16 tmp[8];
#pragma unroll
    for (int j = 0; j < 8; ++j) {
        int kk = ktile * 32 + hi * 8 + j;
        tmp[j] = (kk < rows && n < cols) ? f2bf(src[(size_t)kk * ld + n]) : (u16)0;
    }
    u16* d = dst + (((size_t)(kt0 + ktile) * ntot + (nt0 + ntile)) * 64 + lane) * 8;
    *(bf16x8*)d = *(const bf16x8*)tmp;
}

// one-wave 16x16 GEMM tile, A row-major bf16, B pre-packed
__device__ inline f32x4 gemm_tile(const u16* __restrict__ A, int lda,
                                  const u16* __restrict__ Bp,
                                  int row0, int nt, int ntot, int ktiles) {
    int lane = threadIdx.x & 63;
    int m = lane & 15, hi = lane >> 4;
    const u16* arow = A + (size_t)(row0 + m) * lda + hi * 8;
    const u16* bptr = Bp + ((size_t)nt * 64 + lane) * 8;
    f32x4 acc = {0.f, 0.f, 0.f, 0.f};
#pragma unroll 4
    for (int kt = 0; kt < ktiles; ++kt) {
        bf16x8 a = *(const bf16x8*)(arow + kt * 32);
        bf16x8 b = *(const bf16x8*)(bptr + (size_t)kt * ntot * 512);
        acc = mfma16(a, b, acc);
    }
    return acc;
}

// ---------------- P0: S/recip + embed tail + all packs + cvec ----------------
__global__ __launch_bounds__(256) void kp0(Params p) {
    int w = threadIdx.x >> 6, lane = threadIdx.x & 63;
    int job = blockIdx.x * 4 + w;
    if (job < 256) {
        int k = job;
        int lab[4];
#pragma unroll
        for (int g = 0; g < 4; ++g) {
            int i = lane + g * 64;
            lab[g] = (i == k) ? -1 : p.labels[i * 255 + k - (k > i ? 1 : 0)];
        }
#pragma unroll
        for (int r = 0; r < 6; ++r) {
            int c = 0;
#pragma unroll
            for (int g = 0; g < 4; ++g) c += __popcll(__ballot(lab[g] == r));
#pragma unroll
            for (int g = 0; g < 4; ++g) {
                int i = lane + g * 64;
                p.S[(k * 6 + r) * 256 + i] = (lab[g] == r) ? (u16)0x3F80 : (u16)0;
            }
            if (lane == 0) p.recip[k * 6 + r] = 1.0f / (float)(c > 1 ? c : 1);
        }
    } else if (job < 640) {
        int idx = (job - 256) * 512 + lane * 8;
        int row = idx / 768, col = idx - row * 768;
        f32x4 a = *(const f32x4*)(p.embed + idx);
        f32x4 b = *(const f32x4*)(p.embed + idx + 4);
        u16 tmp[8];
#pragma unroll
        for (int e = 0; e < 4; ++e) { tmp[e] = f2bf(a[e]); tmp[e + 4] = f2bf(b[e]); }
        *(bf16x8*)(p.Acat1 + (size_t)row * KCAT + 4608 + col) = *(const bf16x8*)tmp;
    }
    else if (job < 1024) pack_f32(p.embed, 768, 256, 768, p.Pemb, 48, 0, 0, 48, job - 640);
    else if (job < 7936) pack_f32(p.c1w, 768, 4608, 768, p.PW1, 48, 0, 0, 48, job - 1024);
    else if (job < 9088) pack_f32(p.c1root, 768, 768, 768, p.PW1, 48, 144, 0, 48, job - 7936);
    else if (job < 9328) pack_f32(p.cw1, 150, 768, 150, p.PC1, 20, 0, 0, 10, job - 9088);
    else if (job < 9568) pack_f32(p.cw1 + 768 * 150, 150, 768, 150, p.PC1, 20, 0, 10, 10, job - 9328);
    else if (job < 9618) pack_f32(p.cw2, 150, 150, 150, p.Pw2c, 10, 0, 0, 10, job - 9568);
    else if (job < 9623) pack_f32(p.cw3, 7, 150, 7, p.Pw3, 1, 0, 0, 1, job - 9618);
    else if (job < 9628) {
        // cvec[j] = c2b @ C1cat[:,j] (+ b1[j] on the A-half)
        int j = (job - 9623) * 64 + lane;
        float s = 0.f;
        const float* col;
        bool valid;
        if (j < 160) { valid = (j < 150); col = p.cw1 + j; }
        else         { int q = j - 160; valid = (q < 150); col = p.cw1 + (size_t)768 * 150 + q; }
        if (valid) {
            float acc = 0.f;
            for (int d = 0; d < 768; ++d) acc = fmaf(p.c2b[d], col[(size_t)d * 150], acc);
            s = acc + ((j < 150) ? p.cb1[j] : 0.f);
        }
        p.cvec[j] = s;
    }
}

// ---------------- mean tile: (S @ Bp) * recip -> Acat ----------------
__device__ void mean_tile(const Params& p, const u16* Bp, u16* Acat, int tile) {
    int rt = tile / 48, nt = tile % 48;
    f32x4 acc = gemm_tile(p.S, 256, Bp, rt * 16, nt, 48, 8);
    int lane = threadIdx.x & 63;
    int col = nt * 16 + (lane & 15), hi = lane >> 4;
#pragma unroll
    for (int r = 0; r < 4; ++r) {
        int g = rt * 16 + hi * 4 + r;
        float scale = p.recip[g];
        int node = g / 6, rel = g - node * 6;
        Acat[(size_t)node * KCAT + rel * 768 + col] = f2bf(acc[r] * scale);
    }
}

// ---------------- W2C1 = Wcat2 @ C1cat, output packed as B-fragments -----------
// per wave-job: 32 rows x 64 cols (2 m-frags x 4 n-tiles), K=768; 840 jobs total
__device__ void w2c1_job(const Params& p, int q) {
    int lane = threadIdx.x & 63;
    int mtb = q / 5, ntb = q % 5;
    int m = lane & 15, hi = lane >> 4;
    int row0 = mtb * 32;
    f32x4 acc[2][4];
#pragma unroll
    for (int t = 0; t < 2; ++t)
#pragma unroll
        for (int qq = 0; qq < 4; ++qq) acc[t][qq] = {0.f, 0.f, 0.f, 0.f};
    for (int kt = 0; kt < 24; ++kt) {
        int e0 = kt * 32 + hi * 8;
        bf16x8 a[2];
#pragma unroll
        for (int t = 0; t < 2; ++t) {
            int r = row0 + t * 16 + m;
            const float* src = (r < 4608) ? (p.c2w + (size_t)r * 768)
                                          : (p.c2root + (size_t)(r - 4608) * 768);
            f32x4 x0 = *(const f32x4*)(src + e0);
            f32x4 x1 = *(const f32x4*)(src + e0 + 4);
            u16 tmp[8];
#pragma unroll
            for (int e = 0; e < 4; ++e) { tmp[e] = f2bf(x0[e]); tmp[e + 4] = f2bf(x1[e]); }
            a[t] = *(const bf16x8*)tmp;
        }
#pragma unroll
        for (int qq = 0; qq < 4; ++qq) {
            int nt = ntb * 4 + qq;
            bf16x8 b = *(const bf16x8*)(p.PC1 + ((size_t)(kt * 20 + nt) * 64 + lane) * 8);
            acc[0][qq] = mfma16(a[0], b, acc[0][qq]);
            acc[1][qq] = mfma16(a[1], b, acc[1][qq]);
        }
    }
#pragma unroll
    for (int t = 0; t < 2; ++t)
#pragma unroll
        for (int qq = 0; qq < 4; ++qq) {
            int nt = ntb * 4 + qq;
#pragma unroll
            for (int r4 = 0; r4 < 4; ++r4) {
                int kg = row0 + t * 16 + hi * 4 + r4;
                int kt2 = kg >> 5, j = kg & 7, hi2 = (kg >> 3) & 3;
                p.W2C1p[(((size_t)kt2 * 20 + nt) * 64 + hi2 * 16 + m) * 8 + j] = f2bf(acc[t][qq][r4]);
            }
        }
}

// ---------------- P1: mean1 (4608 jobs) + W2C1 (840 jobs) = 5448 ----------------
__global__ __launch_bounds__(256) void kp1(Params p) {
    int w = threadIdx.x >> 6;
    int job = blockIdx.x * 4 + w;
    if (job < 4608)      mean_tile(p, p.Pemb, p.Acat1, job);
    else if (job < 5448) w2c1_job(p, job - 4608);
}

// ---------------- P2: conv1 = Acat1 @ Wcat1 (K split over 4 waves, LDS reduce) --
__global__ __launch_bounds__(256) void kp2(Params p) {
    __shared__ float red[4 * 64 * 4];
    int w = threadIdx.x >> 6, lane = threadIdx.x & 63;
    int m = lane & 15, hi = lane >> 4;
    int b = blockIdx.x;
    int rt = b / 48, nt = b % 48;
    const u16* arow = p.Acat1 + (size_t)(rt * 16 + m) * KCAT + hi * 8;
    const u16* bptr = p.PW1 + ((size_t)nt * 64 + lane) * 8;
    f32x4 acc = {0.f, 0.f, 0.f, 0.f};
#pragma unroll 4
    for (int kt = w * 42; kt < (w + 1) * 42; ++kt) {
        bf16x8 a = *(const bf16x8*)(arow + kt * 32);
        bf16x8 bb = *(const bf16x8*)(bptr + (size_t)kt * 48 * 512);
        acc = mfma16(a, bb, acc);
    }
    *(f32x4*)&red[(w * 64 + lane) * 4] = acc;
    __syncthreads();
    if (w == 0) {
        f32x4 s = *(f32x4*)&red[lane * 4];
#pragma unroll
        for (int ww = 1; ww < 4; ++ww) s += *(f32x4*)&red[(ww * 64 + lane) * 4];
        int col = nt * 16 + m;
        float bbv = p.c1b[col];
#pragma unroll
        for (int r = 0; r < 4; ++r) {
            int g = rt * 16 + hi * 4 + r;
            float v = fmaxf(s[r] + bbv, 0.f);
            u16 bv = f2bf(v);
            p.Acat2[(size_t)g * KCAT + 4608 + col] = bv;
            p.Px[(((size_t)(g >> 5) * 48 + nt) * 64 + (((g >> 3) & 3) * 16 + m)) * 8 + (g & 7)] = bv;
        }
    }
}

// ---------------- P3: mean2 ----------------
__global__ __launch_bounds__(256) void kp3(Params p) {
    int w = threadIdx.x >> 6;
    int job = blockIdx.x * 4 + w;
    if (job < 4608) mean_tile(p, p.Px, p.Acat2, job);
}

// ---------------- P4: AB = Acat2 @ W2C1p + cvec (K split over 4 waves) ---------
__global__ __launch_bounds__(256) void kp4(Params p) {
    __shared__ float red2[4 * 64 * 4];
    int w = threadIdx.x >> 6, lane = threadIdx.x & 63;
    int m = lane & 15, hi = lane >> 4;
    int b = blockIdx.x;
    int rt = b / 20, nt = b % 20;
    const u16* arow = p.Acat2 + (size_t)(rt * 16 + m) * KCAT + hi * 8;
    const u16* bptr = p.W2C1p + ((size_t)nt * 64 + lane) * 8;
    f32x4 acc = {0.f, 0.f, 0.f, 0.f};
#pragma unroll 4
    for (int kt = w * 42; kt < (w + 1) * 42; ++kt) {
        bf16x8 a = *(const bf16x8*)(arow + kt * 32);
        bf16x8 bb = *(const bf16x8*)(bptr + (size_t)kt * 20 * 512);
        acc = mfma16(a, bb, acc);
    }
    *(f32x4*)&red2[(w * 64 + lane) * 4] = acc;
    __syncthreads();
    if (w == 0) {
        f32x4 s = *(f32x4*)&red2[lane * 4];
#pragma unroll
        for (int ww = 1; ww < 4; ++ww) s += *(f32x4*)&red2[(ww * 64 + lane) * 4];
        int j = nt * 16 + m;
        float cv = p.cvec[j];
#pragma unroll
        for (int r = 0; r < 4; ++r) {
            int g = rt * 16 + hi * 4 + r;
            p.AB[(size_t)g * 320 + j] = s[r] + cv;
        }
    }
}

// ---------------- P5: fused pair MLP ----------------
__global__ __launch_bounds__(256) void kp5(Params p) {
    __shared__ u16 h2t[4][16][168];
    int w = threadIdx.x >> 6, lane = threadIdx.x & 63;
    int m = lane & 15, hi = lane >> 4;
    int pb = blockIdx.x * 64 + w * 16;
    int pp = pb + m;
    int i = pp / 255, rem = pp - i * 255;
    int k = rem + (rem >= i ? 1 : 0);
    const float* Ar = p.AB + (size_t)i * 320;
    const float* Br = p.AB + (size_t)k * 320 + 160;

    bf16x8 af[5];
#pragma unroll
    for (int kk = 0; kk < 5; ++kk) {
        int c = kk * 32 + hi * 8;
        f32x4 a0 = *(const f32x4*)(Ar + c);
        f32x4 a1 = *(const f32x4*)(Ar + c + 4);
        f32x4 b0 = *(const f32x4*)(Br + c);
        f32x4 b1v = *(const f32x4*)(Br + c + 4);
        f32x4 s0 = a0 + b0, s1 = a1 + b1v;
        bf16x8 f;
#pragma unroll
        for (int e = 0; e < 4; ++e) {
            f[e]     = (short)f2bf(fmaxf(s0[e], 0.f));
            f[e + 4] = (short)f2bf(fmaxf(s1[e], 0.f));
        }
        af[kk] = f;
    }

#pragma unroll
    for (int nt = 0; nt < 10; ++nt) {
        f32x4 acc = {0.f, 0.f, 0.f, 0.f};
#pragma unroll
        for (int kk = 0; kk < 5; ++kk) {
            bf16x8 b = *(const bf16x8*)(p.Pw2c + ((size_t)(kk * 10 + nt) * 64 + lane) * 8);
            acc = mfma16(af[kk], b, acc);
        }
        int col = nt * 16 + m;
        float bb = (col < 150) ? p.cb2[col] : 0.f;
#pragma unroll
        for (int r = 0; r < 4; ++r) {
            float v = fmaxf(acc[r] + bb, 0.f);
            h2t[w][hi * 4 + r][col] = f2bf(v);
        }
    }
    __syncthreads();

    f32x4 acc3 = {0.f, 0.f, 0.f, 0.f};
#pragma unroll
    for (int kk = 0; kk < 5; ++kk) {
        bf16x8 a = *(const bf16x8*)(&h2t[w][m][kk * 32 + hi * 8]);
        bf16x8 b = *(const bf16x8*)(p.Pw3 + ((size_t)kk * 64 + lane) * 8);
        acc3 = mfma16(a, b, acc3);
    }
    if (m < 7) {
        float bb = p.cb3[m];
#pragma unroll
        for (int r = 0; r < 4; ++r) {
            int p2 = pb + hi * 4 + r;
            p.outp[p2 * 7 + m] = acc3[r] + bb;
        }
    }
}

extern "C" void kernel_launch(void* const* d_in, const int* in_sizes, int n_in,
                              void* d_out, int out_size, void* d_ws, size_t ws_size,
                              hipStream_t stream) {
    char* ws = (char*)d_ws;
    Params hp;
    hp.embed  = (const float*)d_in[0];
    hp.labels = (const int*)d_in[1];
    hp.c1w    = (const float*)d_in[2];
    hp.c1root = (const float*)d_in[3];
    hp.c1b    = (const float*)d_in[4];
    hp.c2w    = (const float*)d_in[5];
    hp.c2root = (const float*)d_in[6];
    hp.c2b    = (const float*)d_in[7];
    // d_in[8..13] (base_*) are dead code
    hp.cw1    = (const float*)d_in[14];
    hp.cb1    = (const float*)d_in[15];
    hp.cw2    = (const float*)d_in[16];
    hp.cb2    = (const float*)d_in[17];
    hp.cw3    = (const float*)d_in[18];
    hp.cb3    = (const float*)d_in[19];
    hp.S      = (u16*)(ws + 0);            // 786432
    hp.recip  = (float*)(ws + 786432);     // 6144
    hp.Acat1  = (u16*)(ws + 792576);       // 2752512
    hp.Acat2  = (u16*)(ws + 3545088);      // 2752512
    hp.Pemb   = (u16*)(ws + 6297600);      // 393216
    hp.Px     = (u16*)(ws + 6690816);      // 393216
    hp.PW1    = (u16*)(ws + 7084032);      // 8257536
    hp.PC1    = (u16*)(ws + 15341568);     // 491520
    hp.Pw2c   = (u16*)(ws + 15833088);     // 102400
    hp.Pw3    = (u16*)(ws + 15935488);     // 10240
    hp.W2C1p  = (u16*)(ws + 15945728);     // 3440640
    hp.cvec   = (float*)(ws + 19386368);   // 1280
    hp.AB     = (float*)(ws + 19387648);   // 327680
    hp.outp   = (float*)d_out;

    kp0<<<2407, 256, 0, stream>>>(hp);   // setup: S/recip, packs, embed tail, cvec
    kp1<<<1362, 256, 0, stream>>>(hp);   // mean1 (4608) + W2C1 (840)
    kp2<<<768, 256, 0, stream>>>(hp);    // conv1 (+relu, + packed Px)
    kp3<<<1152, 256, 0, stream>>>(hp);   // mean2
    kp4<<<320, 256, 0, stream>>>(hp);    // AB = Acat2 @ W2C1 + cvec
    kp5<<<1020, 256, 0, stream>>>(hp);   // fused pair MLP
}

// Round 8
// 130.964 us; speedup vs baseline: 3.7269x; 1.0641x over previous
//
#include <hip/hip_runtime.h>

typedef unsigned short u16;
typedef unsigned int   u32;
typedef __attribute__((ext_vector_type(8))) short bf16x8;   // 8 bf16 in 4 VGPRs
typedef __attribute__((ext_vector_type(4))) float f32x4;

#define KCAT 5376   // 6*768 (mean) + 768 (root)

struct Params {
    const float* embed; const int* labels;
    const float* c1w; const float* c1root; const float* c1b;
    const float* c2w; const float* c2root; const float* c2b;
    const float* cw1; const float* cb1; const float* cw2;
    const float* cb2; const float* cw3; const float* cb3;
    u16* S; float* recip; u16* Acat1; u16* Acat2;
    u16* Pemb; u16* Px; u16* PW1; u16* PC1; u16* Pw2c; u16* Pw3;
    u16* W2C1p; float* cvec; float* AB; float* outp;
};

__device__ inline u16 f2bf(float f) {
    union { float f; u32 u; } v; v.f = f;
    u32 r = v.u + 0x7FFFu + ((v.u >> 16) & 1u);   // RNE
    return (u16)(r >> 16);
}
__device__ inline f32x4 mfma16(bf16x8 a, bf16x8 b, f32x4 c) {
    return __builtin_amdgcn_mfma_f32_16x16x32_bf16(a, b, c, 0, 0, 0);
}

// pack one 32x16 tile of a row-major f32 matrix into MFMA B-fragment layout (bf16)
__device__ inline void pack_f32(const float* __restrict__ src, int ld, int rows, int cols,
                                u16* __restrict__ dst, int ntot, int kt0, int nt0,
                                int ntiles, int tile) {
    int ktile = tile / ntiles, ntile = tile % ntiles;
    int lane = threadIdx.x & 63;
    int m = lane & 15, hi = lane >> 4;
    int n = ntile * 16 + m;
    u16 tmp[8];
#pragma unroll
    for (int j = 0; j < 8; ++j) {
        int kk = ktile * 32 + hi * 8 + j;
        tmp[j] = (kk < rows && n < cols) ? f2bf(src[(size_t)kk * ld + n]) : (u16)0;
    }
    u16* d = dst + (((size_t)(kt0 + ktile) * ntot + (nt0 + ntile)) * 64 + lane) * 8;
    *(bf16x8*)d = *(const bf16x8*)tmp;
}

// one-wave 16x16 GEMM tile, A row-major bf16, B pre-packed
__device__ inline f32x4 gemm_tile(const u16* __restrict__ A, int lda,
                                  const u16* __restrict__ Bp,
                                  int row0, int nt, int ntot, int ktiles) {
    int lane = threadIdx.x & 63;
    int m = lane & 15, hi = lane >> 4;
    const u16* arow = A + (size_t)(row0 + m) * lda + hi * 8;
    const u16* bptr = Bp + ((size_t)nt * 64 + lane) * 8;
    f32x4 acc = {0.f, 0.f, 0.f, 0.f};
#pragma unroll 4
    for (int kt = 0; kt < ktiles; ++kt) {
        bf16x8 a = *(const bf16x8*)(arow + kt * 32);
        bf16x8 b = *(const bf16x8*)(bptr + (size_t)kt * ntot * 512);
        acc = mfma16(a, b, acc);
    }
    return acc;
}

// ---------------- P0: S/recip + embed tail + all packs + cvec ----------------
__global__ __launch_bounds__(256) void kp0(Params p) {
    int w = threadIdx.x >> 6, lane = threadIdx.x & 63;
    int job = blockIdx.x * 4 + w;
    if (job < 256) {
        int k = job;
        int lab[4];
#pragma unroll
        for (int g = 0; g < 4; ++g) {
            int i = lane + g * 64;
            lab[g] = (i == k) ? -1 : p.labels[i * 255 + k - (k > i ? 1 : 0)];
        }
#pragma unroll
        for (int r = 0; r < 6; ++r) {
            int c = 0;
#pragma unroll
            for (int g = 0; g < 4; ++g) c += __popcll(__ballot(lab[g] == r));
#pragma unroll
            for (int g = 0; g < 4; ++g) {
                int i = lane + g * 64;
                p.S[(k * 6 + r) * 256 + i] = (lab[g] == r) ? (u16)0x3F80 : (u16)0;
            }
            if (lane == 0) p.recip[k * 6 + r] = 1.0f / (float)(c > 1 ? c : 1);
        }
    } else if (job < 640) {
        int idx = (job - 256) * 512 + lane * 8;
        int row = idx / 768, col = idx - row * 768;
        f32x4 a = *(const f32x4*)(p.embed + idx);
        f32x4 b = *(const f32x4*)(p.embed + idx + 4);
        u16 tmp[8];
#pragma unroll
        for (int e = 0; e < 4; ++e) { tmp[e] = f2bf(a[e]); tmp[e + 4] = f2bf(b[e]); }
        *(bf16x8*)(p.Acat1 + (size_t)row * KCAT + 4608 + col) = *(const bf16x8*)tmp;
    }
    else if (job < 1024) pack_f32(p.embed, 768, 256, 768, p.Pemb, 48, 0, 0, 48, job - 640);
    else if (job < 7936) pack_f32(p.c1w, 768, 4608, 768, p.PW1, 48, 0, 0, 48, job - 1024);
    else if (job < 9088) pack_f32(p.c1root, 768, 768, 768, p.PW1, 48, 144, 0, 48, job - 7936);
    else if (job < 9328) pack_f32(p.cw1, 150, 768, 150, p.PC1, 20, 0, 0, 10, job - 9088);
    else if (job < 9568) pack_f32(p.cw1 + 768 * 150, 150, 768, 150, p.PC1, 20, 0, 10, 10, job - 9328);
    else if (job < 9618) pack_f32(p.cw2, 150, 150, 150, p.Pw2c, 10, 0, 0, 10, job - 9568);
    else if (job < 9623) pack_f32(p.cw3, 7, 150, 7, p.Pw3, 1, 0, 0, 1, job - 9618);
    else if (job < 9628) {
        // cvec[j] = c2b @ C1cat[:,j] (+ b1[j] on the A-half)
        // 8 independent fmaf chains (depth 96) instead of one depth-768 chain:
        // the serial-latency straggler that held kp0 at ~45us.
        int j = (job - 9623) * 64 + lane;
        float s = 0.f;
        const float* col;
        bool valid;
        if (j < 160) { valid = (j < 150); col = p.cw1 + j; }
        else         { int q = j - 160; valid = (q < 150); col = p.cw1 + (size_t)768 * 150 + q; }
        if (valid) {
            float a0 = 0.f, a1 = 0.f, a2 = 0.f, a3 = 0.f;
            float a4 = 0.f, a5 = 0.f, a6 = 0.f, a7 = 0.f;
            for (int d = 0; d < 768; d += 8) {
                a0 = fmaf(p.c2b[d],     col[(size_t)(d)     * 150], a0);
                a1 = fmaf(p.c2b[d + 1], col[(size_t)(d + 1) * 150], a1);
                a2 = fmaf(p.c2b[d + 2], col[(size_t)(d + 2) * 150], a2);
                a3 = fmaf(p.c2b[d + 3], col[(size_t)(d + 3) * 150], a3);
                a4 = fmaf(p.c2b[d + 4], col[(size_t)(d + 4) * 150], a4);
                a5 = fmaf(p.c2b[d + 5], col[(size_t)(d + 5) * 150], a5);
                a6 = fmaf(p.c2b[d + 6], col[(size_t)(d + 6) * 150], a6);
                a7 = fmaf(p.c2b[d + 7], col[(size_t)(d + 7) * 150], a7);
            }
            s = ((a0 + a1) + (a2 + a3)) + ((a4 + a5) + (a6 + a7));
            s += (j < 150) ? p.cb1[j] : 0.f;
        }
        p.cvec[j] = s;
    }
}

// ---------------- mean tile: (S @ Bp) * recip -> Acat ----------------
__device__ void mean_tile(const Params& p, const u16* Bp, u16* Acat, int tile) {
    int rt = tile / 48, nt = tile % 48;
    f32x4 acc = gemm_tile(p.S, 256, Bp, rt * 16, nt, 48, 8);
    int lane = threadIdx.x & 63;
    int col = nt * 16 + (lane & 15), hi = lane >> 4;
#pragma unroll
    for (int r = 0; r < 4; ++r) {
        int g = rt * 16 + hi * 4 + r;
        float scale = p.recip[g];
        int node = g / 6, rel = g - node * 6;
        Acat[(size_t)node * KCAT + rel * 768 + col] = f2bf(acc[r] * scale);
    }
}

// ---------------- W2C1 = Wcat2 @ C1cat, output packed as B-fragments -----------
// per wave-job: 32 rows x 64 cols (2 m-frags x 4 n-tiles), K=768; 840 jobs total
__device__ void w2c1_job(const Params& p, int q) {
    int lane = threadIdx.x & 63;
    int mtb = q / 5, ntb = q % 5;
    int m = lane & 15, hi = lane >> 4;
    int row0 = mtb * 32;
    f32x4 acc[2][4];
#pragma unroll
    for (int t = 0; t < 2; ++t)
#pragma unroll
        for (int qq = 0; qq < 4; ++qq) acc[t][qq] = {0.f, 0.f, 0.f, 0.f};
    for (int kt = 0; kt < 24; ++kt) {
        int e0 = kt * 32 + hi * 8;
        bf16x8 a[2];
#pragma unroll
        for (int t = 0; t < 2; ++t) {
            int r = row0 + t * 16 + m;
            const float* src = (r < 4608) ? (p.c2w + (size_t)r * 768)
                                          : (p.c2root + (size_t)(r - 4608) * 768);
            f32x4 x0 = *(const f32x4*)(src + e0);
            f32x4 x1 = *(const f32x4*)(src + e0 + 4);
            u16 tmp[8];
#pragma unroll
            for (int e = 0; e < 4; ++e) { tmp[e] = f2bf(x0[e]); tmp[e + 4] = f2bf(x1[e]); }
            a[t] = *(const bf16x8*)tmp;
        }
#pragma unroll
        for (int qq = 0; qq < 4; ++qq) {
            int nt = ntb * 4 + qq;
            bf16x8 b = *(const bf16x8*)(p.PC1 + ((size_t)(kt * 20 + nt) * 64 + lane) * 8);
            acc[0][qq] = mfma16(a[0], b, acc[0][qq]);
            acc[1][qq] = mfma16(a[1], b, acc[1][qq]);
        }
    }
#pragma unroll
    for (int t = 0; t < 2; ++t)
#pragma unroll
        for (int qq = 0; qq < 4; ++qq) {
            int nt = ntb * 4 + qq;
#pragma unroll
            for (int r4 = 0; r4 < 4; ++r4) {
                int kg = row0 + t * 16 + hi * 4 + r4;
                int kt2 = kg >> 5, j = kg & 7, hi2 = (kg >> 3) & 3;
                p.W2C1p[(((size_t)kt2 * 20 + nt) * 64 + hi2 * 16 + m) * 8 + j] = f2bf(acc[t][qq][r4]);
            }
        }
}

// ---------------- P1: mean1 (4608 jobs) + W2C1 (840 jobs) = 5448 ----------------
__global__ __launch_bounds__(256) void kp1(Params p) {
    int w = threadIdx.x >> 6;
    int job = blockIdx.x * 4 + w;
    if (job < 4608)      mean_tile(p, p.Pemb, p.Acat1, job);
    else if (job < 5448) w2c1_job(p, job - 4608);
}

// ---------------- P2: conv1 = Acat1 @ Wcat1 (K split over 4 waves, LDS reduce) --
__global__ __launch_bounds__(256) void kp2(Params p) {
    __shared__ float red[4 * 64 * 4];
    int w = threadIdx.x >> 6, lane = threadIdx.x & 63;
    int m = lane & 15, hi = lane >> 4;
    int b = blockIdx.x;
    int rt = b / 48, nt = b % 48;
    const u16* arow = p.Acat1 + (size_t)(rt * 16 + m) * KCAT + hi * 8;
    const u16* bptr = p.PW1 + ((size_t)nt * 64 + lane) * 8;
    f32x4 acc = {0.f, 0.f, 0.f, 0.f};
#pragma unroll 4
    for (int kt = w * 42; kt < (w + 1) * 42; ++kt) {
        bf16x8 a = *(const bf16x8*)(arow + kt * 32);
        bf16x8 bb = *(const bf16x8*)(bptr + (size_t)kt * 48 * 512);
        acc = mfma16(a, bb, acc);
    }
    *(f32x4*)&red[(w * 64 + lane) * 4] = acc;
    __syncthreads();
    if (w == 0) {
        f32x4 s = *(f32x4*)&red[lane * 4];
#pragma unroll
        for (int ww = 1; ww < 4; ++ww) s += *(f32x4*)&red[(ww * 64 + lane) * 4];
        int col = nt * 16 + m;
        float bbv = p.c1b[col];
#pragma unroll
        for (int r = 0; r < 4; ++r) {
            int g = rt * 16 + hi * 4 + r;
            float v = fmaxf(s[r] + bbv, 0.f);
            u16 bv = f2bf(v);
            p.Acat2[(size_t)g * KCAT + 4608 + col] = bv;
            p.Px[(((size_t)(g >> 5) * 48 + nt) * 64 + (((g >> 3) & 3) * 16 + m)) * 8 + (g & 7)] = bv;
        }
    }
}

// ---------------- P3: mean2 ----------------
__global__ __launch_bounds__(256) void kp3(Params p) {
    int w = threadIdx.x >> 6;
    int job = blockIdx.x * 4 + w;
    if (job < 4608) mean_tile(p, p.Px, p.Acat2, job);
}

// ---------------- P4: AB = Acat2 @ W2C1p + cvec (K split over 4 waves) ---------
__global__ __launch_bounds__(256) void kp4(Params p) {
    __shared__ float red2[4 * 64 * 4];
    int w = threadIdx.x >> 6, lane = threadIdx.x & 63;
    int m = lane & 15, hi = lane >> 4;
    int b = blockIdx.x;
    int rt = b / 20, nt = b % 20;
    const u16* arow = p.Acat2 + (size_t)(rt * 16 + m) * KCAT + hi * 8;
    const u16* bptr = p.W2C1p + ((size_t)nt * 64 + lane) * 8;
    f32x4 acc = {0.f, 0.f, 0.f, 0.f};
#pragma unroll 4
    for (int kt = w * 42; kt < (w + 1) * 42; ++kt) {
        bf16x8 a = *(const bf16x8*)(arow + kt * 32);
        bf16x8 bb = *(const bf16x8*)(bptr + (size_t)kt * 20 * 512);
        acc = mfma16(a, bb, acc);
    }
    *(f32x4*)&red2[(w * 64 + lane) * 4] = acc;
    __syncthreads();
    if (w == 0) {
        f32x4 s = *(f32x4*)&red2[lane * 4];
#pragma unroll
        for (int ww = 1; ww < 4; ++ww) s += *(f32x4*)&red2[(ww * 64 + lane) * 4];
        int j = nt * 16 + m;
        float cv = p.cvec[j];
#pragma unroll
        for (int r = 0; r < 4; ++r) {
            int g = rt * 16 + hi * 4 + r;
            p.AB[(size_t)g * 320 + j] = s[r] + cv;
        }
    }
}

// ---------------- P5: fused pair MLP ----------------
__global__ __launch_bounds__(256) void kp5(Params p) {
    __shared__ u16 h2t[4][16][168];
    int w = threadIdx.x >> 6, lane = threadIdx.x & 63;
    int m = lane & 15, hi = lane >> 4;
    int pb = blockIdx.x * 64 + w * 16;
    int pp = pb + m;
    int i = pp / 255, rem = pp - i * 255;
    int k = rem + (rem >= i ? 1 : 0);
    const float* Ar = p.AB + (size_t)i * 320;
    const float* Br = p.AB + (size_t)k * 320 + 160;

    bf16x8 af[5];
#pragma unroll
    for (int kk = 0; kk < 5; ++kk) {
        int c = kk * 32 + hi * 8;
        f32x4 a0 = *(const f32x4*)(Ar + c);
        f32x4 a1 = *(const f32x4*)(Ar + c + 4);
        f32x4 b0 = *(const f32x4*)(Br + c);
        f32x4 b1v = *(const f32x4*)(Br + c + 4);
        f32x4 s0 = a0 + b0, s1 = a1 + b1v;
        bf16x8 f;
#pragma unroll
        for (int e = 0; e < 4; ++e) {
            f[e]     = (short)f2bf(fmaxf(s0[e], 0.f));
            f[e + 4] = (short)f2bf(fmaxf(s1[e], 0.f));
        }
        af[kk] = f;
    }

#pragma unroll
    for (int nt = 0; nt < 10; ++nt) {
        f32x4 acc = {0.f, 0.f, 0.f, 0.f};
#pragma unroll
        for (int kk = 0; kk < 5; ++kk) {
            bf16x8 b = *(const bf16x8*)(p.Pw2c + ((size_t)(kk * 10 + nt) * 64 + lane) * 8);
            acc = mfma16(af[kk], b, acc);
        }
        int col = nt * 16 + m;
        float bb = (col < 150) ? p.cb2[col] : 0.f;
#pragma unroll
        for (int r = 0; r < 4; ++r) {
            float v = fmaxf(acc[r] + bb, 0.f);
            h2t[w][hi * 4 + r][col] = f2bf(v);
        }
    }
    __syncthreads();

    f32x4 acc3 = {0.f, 0.f, 0.f, 0.f};
#pragma unroll
    for (int kk = 0; kk < 5; ++kk) {
        bf16x8 a = *(const bf16x8*)(&h2t[w][m][kk * 32 + hi * 8]);
        bf16x8 b = *(const bf16x8*)(p.Pw3 + ((size_t)kk * 64 + lane) * 8);
        acc3 = mfma16(a, b, acc3);
    }
    if (m < 7) {
        float bb = p.cb3[m];
#pragma unroll
        for (int r = 0; r < 4; ++r) {
            int p2 = pb + hi * 4 + r;
            p.outp[p2 * 7 + m] = acc3[r] + bb;
        }
    }
}

extern "C" void kernel_launch(void* const* d_in, const int* in_sizes, int n_in,
                              void* d_out, int out_size, void* d_ws, size_t ws_size,
                              hipStream_t stream) {
    char* ws = (char*)d_ws;
    Params hp;
    hp.embed  = (const float*)d_in[0];
    hp.labels = (const int*)d_in[1];
    hp.c1w    = (const float*)d_in[2];
    hp.c1root = (const float*)d_in[3];
    hp.c1b    = (const float*)d_in[4];
    hp.c2w    = (const float*)d_in[5];
    hp.c2root = (const float*)d_in[6];
    hp.c2b    = (const float*)d_in[7];
    // d_in[8..13] (base_*) are dead code
    hp.cw1    = (const float*)d_in[14];
    hp.cb1    = (const float*)d_in[15];
    hp.cw2    = (const float*)d_in[16];
    hp.cb2    = (const float*)d_in[17];
    hp.cw3    = (const float*)d_in[18];
    hp.cb3    = (const float*)d_in[19];
    hp.S      = (u16*)(ws + 0);            // 786432
    hp.recip  = (float*)(ws + 786432);     // 6144
    hp.Acat1  = (u16*)(ws + 792576);       // 2752512
    hp.Acat2  = (u16*)(ws + 3545088);      // 2752512
    hp.Pemb   = (u16*)(ws + 6297600);      // 393216
    hp.Px     = (u16*)(ws + 6690816);      // 393216
    hp.PW1    = (u16*)(ws + 7084032);      // 8257536
    hp.PC1    = (u16*)(ws + 15341568);     // 491520
    hp.Pw2c   = (u16*)(ws + 15833088);     // 102400
    hp.Pw3    = (u16*)(ws + 15935488);     // 10240
    hp.W2C1p  = (u16*)(ws + 15945728);     // 3440640
    hp.cvec   = (float*)(ws + 19386368);   // 1280
    hp.AB     = (float*)(ws + 19387648);   // 327680
    hp.outp   = (float*)d_out;

    kp0<<<2407, 256, 0, stream>>>(hp);   // setup: S/recip, packs, embed tail, cvec (ILP'd)
    kp1<<<1362, 256, 0, stream>>>(hp);   // mean1 (4608) + W2C1 (840)
    kp2<<<768, 256, 0, stream>>>(hp);    // conv1 (+relu, + packed Px)
    kp3<<<1152, 256, 0, stream>>>(hp);   // mean2
    kp4<<<320, 256, 0, stream>>>(hp);    // AB = Acat2 @ W2C1 + cvec
    kp5<<<1020, 256, 0, stream>>>(hp);   // fused pair MLP
}

// Round 9
// 103.101 us; speedup vs baseline: 4.7340x; 1.2702x over previous
//
#include <hip/hip_runtime.h>

typedef unsigned short u16;
typedef unsigned int   u32;
typedef __attribute__((ext_vector_type(8))) short bf16x8;   // 8 bf16 in 4 VGPRs
typedef __attribute__((ext_vector_type(4))) float f32x4;

#define KCAT 5376   // 6*768 (mean) + 768 (root)

struct Params {
    const float* embed; const int* labels;
    const float* c1w; const float* c1root; const float* c1b;
    const float* c2w; const float* c2root; const float* c2b;
    const float* cw1; const float* cb1; const float* cw2;
    const float* cb2; const float* cw3; const float* cb3;
    u16* S; float* recip; u16* Acat1; u16* Acat2;
    u16* Pemb; u16* Px; u16* PW1; u16* PC1; u16* Pw2c; u16* Pw3;
    u16* W2C1p; float* cvec; float* AB; float* outp;
};

__device__ inline u16 f2bf(float f) {
    union { float f; u32 u; } v; v.f = f;
    u32 r = v.u + 0x7FFFu + ((v.u >> 16) & 1u);   // RNE
    return (u16)(r >> 16);
}
__device__ inline f32x4 mfma16(bf16x8 a, bf16x8 b, f32x4 c) {
    return __builtin_amdgcn_mfma_f32_16x16x32_bf16(a, b, c, 0, 0, 0);
}

// pack one 32x16 tile of a row-major f32 matrix into MFMA B-fragment layout (bf16)
__device__ inline void pack_f32(const float* __restrict__ src, int ld, int rows, int cols,
                                u16* __restrict__ dst, int ntot, int kt0, int nt0,
                                int ntiles, int tile) {
    int ktile = tile / ntiles, ntile = tile % ntiles;
    int lane = threadIdx.x & 63;
    int m = lane & 15, hi = lane >> 4;
    int n = ntile * 16 + m;
    u16 tmp[8];
#pragma unroll
    for (int j = 0; j < 8; ++j) {
        int kk = ktile * 32 + hi * 8 + j;
        tmp[j] = (kk < rows && n < cols) ? f2bf(src[(size_t)kk * ld + n]) : (u16)0;
    }
    u16* d = dst + (((size_t)(kt0 + ktile) * ntot + (nt0 + ntile)) * 64 + lane) * 8;
    *(bf16x8*)d = *(const bf16x8*)tmp;
}

// one-wave 16x16 GEMM tile, A row-major bf16, B pre-packed
__device__ inline f32x4 gemm_tile(const u16* __restrict__ A, int lda,
                                  const u16* __restrict__ Bp,
                                  int row0, int nt, int ntot, int ktiles) {
    int lane = threadIdx.x & 63;
    int m = lane & 15, hi = lane >> 4;
    const u16* arow = A + (size_t)(row0 + m) * lda + hi * 8;
    const u16* bptr = Bp + ((size_t)nt * 64 + lane) * 8;
    f32x4 acc = {0.f, 0.f, 0.f, 0.f};
#pragma unroll 4
    for (int kt = 0; kt < ktiles; ++kt) {
        bf16x8 a = *(const bf16x8*)(arow + kt * 32);
        bf16x8 b = *(const bf16x8*)(bptr + (size_t)kt * ntot * 512);
        acc = mfma16(a, b, acc);
    }
    return acc;
}

// ---------------- P0: S/recip + embed tail + all packs ----------------
__global__ __launch_bounds__(256) void kp0(Params p) {
    int w = threadIdx.x >> 6, lane = threadIdx.x & 63;
    int job = blockIdx.x * 4 + w;
    if (job < 256) {
        int k = job;
        int lab[4];
#pragma unroll
        for (int g = 0; g < 4; ++g) {
            int i = lane + g * 64;
            lab[g] = (i == k) ? -1 : p.labels[i * 255 + k - (k > i ? 1 : 0)];
        }
#pragma unroll
        for (int r = 0; r < 6; ++r) {
            int c = 0;
#pragma unroll
            for (int g = 0; g < 4; ++g) c += __popcll(__ballot(lab[g] == r));
#pragma unroll
            for (int g = 0; g < 4; ++g) {
                int i = lane + g * 64;
                p.S[(k * 6 + r) * 256 + i] = (lab[g] == r) ? (u16)0x3F80 : (u16)0;
            }
            if (lane == 0) p.recip[k * 6 + r] = 1.0f / (float)(c > 1 ? c : 1);
        }
    } else if (job < 640) {
        int idx = (job - 256) * 512 + lane * 8;
        int row = idx / 768, col = idx - row * 768;
        f32x4 a = *(const f32x4*)(p.embed + idx);
        f32x4 b = *(const f32x4*)(p.embed + idx + 4);
        u16 tmp[8];
#pragma unroll
        for (int e = 0; e < 4; ++e) { tmp[e] = f2bf(a[e]); tmp[e + 4] = f2bf(b[e]); }
        *(bf16x8*)(p.Acat1 + (size_t)row * KCAT + 4608 + col) = *(const bf16x8*)tmp;
    }
    else if (job < 1024) pack_f32(p.embed, 768, 256, 768, p.Pemb, 48, 0, 0, 48, job - 640);
    else if (job < 7936) pack_f32(p.c1w, 768, 4608, 768, p.PW1, 48, 0, 0, 48, job - 1024);
    else if (job < 9088) pack_f32(p.c1root, 768, 768, 768, p.PW1, 48, 144, 0, 48, job - 7936);
    else if (job < 9328) pack_f32(p.cw1, 150, 768, 150, p.PC1, 20, 0, 0, 10, job - 9088);
    else if (job < 9568) pack_f32(p.cw1 + 768 * 150, 150, 768, 150, p.PC1, 20, 0, 10, 10, job - 9328);
    else if (job < 9618) pack_f32(p.cw2, 150, 150, 150, p.Pw2c, 10, 0, 0, 10, job - 9568);
    else if (job < 9623) pack_f32(p.cw3, 7, 150, 7, p.Pw3, 1, 0, 0, 1, job - 9618);
}

// ---------------- mean tile: (S @ Bp) * recip -> Acat ----------------
__device__ void mean_tile(const Params& p, const u16* Bp, u16* Acat, int tile) {
    int rt = tile / 48, nt = tile % 48;
    f32x4 acc = gemm_tile(p.S, 256, Bp, rt * 16, nt, 48, 8);
    int lane = threadIdx.x & 63;
    int col = nt * 16 + (lane & 15), hi = lane >> 4;
#pragma unroll
    for (int r = 0; r < 4; ++r) {
        int g = rt * 16 + hi * 4 + r;
        float scale = p.recip[g];
        int node = g / 6, rel = g - node * 6;
        Acat[(size_t)node * KCAT + rel * 768 + col] = f2bf(acc[r] * scale);
    }
}

// ---------------- W2C1 = Wcat2 @ C1cat, output packed as B-fragments -----------
// per wave-job: 32 rows x 64 cols (2 m-frags x 4 n-tiles), K=768; 840 jobs total
__device__ void w2c1_job(const Params& p, int q) {
    int lane = threadIdx.x & 63;
    int mtb = q / 5, ntb = q % 5;
    int m = lane & 15, hi = lane >> 4;
    int row0 = mtb * 32;
    f32x4 acc[2][4];
#pragma unroll
    for (int t = 0; t < 2; ++t)
#pragma unroll
        for (int qq = 0; qq < 4; ++qq) acc[t][qq] = {0.f, 0.f, 0.f, 0.f};
    for (int kt = 0; kt < 24; ++kt) {
        int e0 = kt * 32 + hi * 8;
        bf16x8 a[2];
#pragma unroll
        for (int t = 0; t < 2; ++t) {
            int r = row0 + t * 16 + m;
            const float* src = (r < 4608) ? (p.c2w + (size_t)r * 768)
                                          : (p.c2root + (size_t)(r - 4608) * 768);
            f32x4 x0 = *(const f32x4*)(src + e0);
            f32x4 x1 = *(const f32x4*)(src + e0 + 4);
            u16 tmp[8];
#pragma unroll
            for (int e = 0; e < 4; ++e) { tmp[e] = f2bf(x0[e]); tmp[e + 4] = f2bf(x1[e]); }
            a[t] = *(const bf16x8*)tmp;
        }
#pragma unroll
        for (int qq = 0; qq < 4; ++qq) {
            int nt = ntb * 4 + qq;
            bf16x8 b = *(const bf16x8*)(p.PC1 + ((size_t)(kt * 20 + nt) * 64 + lane) * 8);
            acc[0][qq] = mfma16(a[0], b, acc[0][qq]);
            acc[1][qq] = mfma16(a[1], b, acc[1][qq]);
        }
    }
#pragma unroll
    for (int t = 0; t < 2; ++t)
#pragma unroll
        for (int qq = 0; qq < 4; ++qq) {
            int nt = ntb * 4 + qq;
#pragma unroll
            for (int r4 = 0; r4 < 4; ++r4) {
                int kg = row0 + t * 16 + hi * 4 + r4;
                int kt2 = kg >> 5, j = kg & 7, hi2 = (kg >> 3) & 3;
                p.W2C1p[(((size_t)kt2 * 20 + nt) * 64 + hi2 * 16 + m) * 8 + j] = f2bf(acc[t][qq][r4]);
            }
        }
}

// ---------------- cvec via MFMA: cvec = c2b @ C1cat (+ b1 on A-half) -----------
// one wave per n-tile (20 jobs); A-fragment = c2b in row 0, zeros elsewhere;
// 24 independent B-loads from PC1 (one latency round trip, no serial chain).
__device__ void cvec_job(const Params& p, int nt) {
    int lane = threadIdx.x & 63;
    int m = lane & 15, hi = lane >> 4;
    f32x4 acc = {0.f, 0.f, 0.f, 0.f};
    for (int kt = 0; kt < 24; ++kt) {
        int e0 = kt * 32 + hi * 8;
        f32x4 x0 = *(const f32x4*)(p.c2b + e0);
        f32x4 x1 = *(const f32x4*)(p.c2b + e0 + 4);
        u16 tmp[8];
#pragma unroll
        for (int e = 0; e < 4; ++e) {
            tmp[e]     = (m == 0) ? f2bf(x0[e]) : (u16)0;
            tmp[e + 4] = (m == 0) ? f2bf(x1[e]) : (u16)0;
        }
        bf16x8 a = *(const bf16x8*)tmp;
        bf16x8 b = *(const bf16x8*)(p.PC1 + ((size_t)(kt * 20 + nt) * 64 + lane) * 8);
        acc = mfma16(a, b, acc);
    }
    if (lane < 16) {                        // D row 0 = lanes 0..15, reg 0
        int j = nt * 16 + lane;
        float bias = (j < 150) ? p.cb1[j] : 0.f;   // b1 on A-half only; pads stay 0
        p.cvec[j] = acc[0] + bias;
    }
}

// ---------------- P1: mean1 (4608) + W2C1 (840) + cvec (20) = 5468 -------------
__global__ __launch_bounds__(256) void kp1(Params p) {
    int w = threadIdx.x >> 6;
    int job = blockIdx.x * 4 + w;
    if (job < 4608)      mean_tile(p, p.Pemb, p.Acat1, job);
    else if (job < 5448) w2c1_job(p, job - 4608);
    else if (job < 5468) cvec_job(p, job - 5448);
}

// ---------------- P2: conv1 = Acat1 @ Wcat1 (K split over 4 waves, LDS reduce) --
__global__ __launch_bounds__(256) void kp2(Params p) {
    __shared__ float red[4 * 64 * 4];
    int w = threadIdx.x >> 6, lane = threadIdx.x & 63;
    int m = lane & 15, hi = lane >> 4;
    int b = blockIdx.x;
    int rt = b / 48, nt = b % 48;
    const u16* arow = p.Acat1 + (size_t)(rt * 16 + m) * KCAT + hi * 8;
    const u16* bptr = p.PW1 + ((size_t)nt * 64 + lane) * 8;
    f32x4 acc = {0.f, 0.f, 0.f, 0.f};
#pragma unroll 4
    for (int kt = w * 42; kt < (w + 1) * 42; ++kt) {
        bf16x8 a = *(const bf16x8*)(arow + kt * 32);
        bf16x8 bb = *(const bf16x8*)(bptr + (size_t)kt * 48 * 512);
        acc = mfma16(a, bb, acc);
    }
    *(f32x4*)&red[(w * 64 + lane) * 4] = acc;
    __syncthreads();
    if (w == 0) {
        f32x4 s = *(f32x4*)&red[lane * 4];
#pragma unroll
        for (int ww = 1; ww < 4; ++ww) s += *(f32x4*)&red[(ww * 64 + lane) * 4];
        int col = nt * 16 + m;
        float bbv = p.c1b[col];
#pragma unroll
        for (int r = 0; r < 4; ++r) {
            int g = rt * 16 + hi * 4 + r;
            float v = fmaxf(s[r] + bbv, 0.f);
            u16 bv = f2bf(v);
            p.Acat2[(size_t)g * KCAT + 4608 + col] = bv;
            p.Px[(((size_t)(g >> 5) * 48 + nt) * 64 + (((g >> 3) & 3) * 16 + m)) * 8 + (g & 7)] = bv;
        }
    }
}

// ---------------- P3: mean2 ----------------
__global__ __launch_bounds__(256) void kp3(Params p) {
    int w = threadIdx.x >> 6;
    int job = blockIdx.x * 4 + w;
    if (job < 4608) mean_tile(p, p.Px, p.Acat2, job);
}

// ---------------- P4: AB = Acat2 @ W2C1p + cvec (K split over 4 waves) ---------
__global__ __launch_bounds__(256) void kp4(Params p) {
    __shared__ float red2[4 * 64 * 4];
    int w = threadIdx.x >> 6, lane = threadIdx.x & 63;
    int m = lane & 15, hi = lane >> 4;
    int b = blockIdx.x;
    int rt = b / 20, nt = b % 20;
    const u16* arow = p.Acat2 + (size_t)(rt * 16 + m) * KCAT + hi * 8;
    const u16* bptr = p.W2C1p + ((size_t)nt * 64 + lane) * 8;
    f32x4 acc = {0.f, 0.f, 0.f, 0.f};
#pragma unroll 4
    for (int kt = w * 42; kt < (w + 1) * 42; ++kt) {
        bf16x8 a = *(const bf16x8*)(arow + kt * 32);
        bf16x8 bb = *(const bf16x8*)(bptr + (size_t)kt * 20 * 512);
        acc = mfma16(a, bb, acc);
    }
    *(f32x4*)&red2[(w * 64 + lane) * 4] = acc;
    __syncthreads();
    if (w == 0) {
        f32x4 s = *(f32x4*)&red2[lane * 4];
#pragma unroll
        for (int ww = 1; ww < 4; ++ww) s += *(f32x4*)&red2[(ww * 64 + lane) * 4];
        int j = nt * 16 + m;
        float cv = p.cvec[j];
#pragma unroll
        for (int r = 0; r < 4; ++r) {
            int g = rt * 16 + hi * 4 + r;
            p.AB[(size_t)g * 320 + j] = s[r] + cv;
        }
    }
}

// ---------------- P5: fused pair MLP ----------------
__global__ __launch_bounds__(256) void kp5(Params p) {
    __shared__ u16 h2t[4][16][168];
    int w = threadIdx.x >> 6, lane = threadIdx.x & 63;
    int m = lane & 15, hi = lane >> 4;
    int pb = blockIdx.x * 64 + w * 16;
    int pp = pb + m;
    int i = pp / 255, rem = pp - i * 255;
    int k = rem + (rem >= i ? 1 : 0);
    const float* Ar = p.AB + (size_t)i * 320;
    const float* Br = p.AB + (size_t)k * 320 + 160;

    bf16x8 af[5];
#pragma unroll
    for (int kk = 0; kk < 5; ++kk) {
        int c = kk * 32 + hi * 8;
        f32x4 a0 = *(const f32x4*)(Ar + c);
        f32x4 a1 = *(const f32x4*)(Ar + c + 4);
        f32x4 b0 = *(const f32x4*)(Br + c);
        f32x4 b1v = *(const f32x4*)(Br + c + 4);
        f32x4 s0 = a0 + b0, s1 = a1 + b1v;
        bf16x8 f;
#pragma unroll
        for (int e = 0; e < 4; ++e) {
            f[e]     = (short)f2bf(fmaxf(s0[e], 0.f));
            f[e + 4] = (short)f2bf(fmaxf(s1[e], 0.f));
        }
        af[kk] = f;
    }

#pragma unroll
    for (int nt = 0; nt < 10; ++nt) {
        f32x4 acc = {0.f, 0.f, 0.f, 0.f};
#pragma unroll
        for (int kk = 0; kk < 5; ++kk) {
            bf16x8 b = *(const bf16x8*)(p.Pw2c + ((size_t)(kk * 10 + nt) * 64 + lane) * 8);
            acc = mfma16(af[kk], b, acc);
        }
        int col = nt * 16 + m;
        float bb = (col < 150) ? p.cb2[col] : 0.f;
#pragma unroll
        for (int r = 0; r < 4; ++r) {
            float v = fmaxf(acc[r] + bb, 0.f);
            h2t[w][hi * 4 + r][col] = f2bf(v);
        }
    }
    __syncthreads();

    f32x4 acc3 = {0.f, 0.f, 0.f, 0.f};
#pragma unroll
    for (int kk = 0; kk < 5; ++kk) {
        bf16x8 a = *(const bf16x8*)(&h2t[w][m][kk * 32 + hi * 8]);
        bf16x8 b = *(const bf16x8*)(p.Pw3 + ((size_t)kk * 64 + lane) * 8);
        acc3 = mfma16(a, b, acc3);
    }
    if (m < 7) {
        float bb = p.cb3[m];
#pragma unroll
        for (int r = 0; r < 4; ++r) {
            int p2 = pb + hi * 4 + r;
            p.outp[p2 * 7 + m] = acc3[r] + bb;
        }
    }
}

extern "C" void kernel_launch(void* const* d_in, const int* in_sizes, int n_in,
                              void* d_out, int out_size, void* d_ws, size_t ws_size,
                              hipStream_t stream) {
    char* ws = (char*)d_ws;
    Params hp;
    hp.embed  = (const float*)d_in[0];
    hp.labels = (const int*)d_in[1];
    hp.c1w    = (const float*)d_in[2];
    hp.c1root = (const float*)d_in[3];
    hp.c1b    = (const float*)d_in[4];
    hp.c2w    = (const float*)d_in[5];
    hp.c2root = (const float*)d_in[6];
    hp.c2b    = (const float*)d_in[7];
    // d_in[8..13] (base_*) are dead code
    hp.cw1    = (const float*)d_in[14];
    hp.cb1    = (const float*)d_in[15];
    hp.cw2    = (const float*)d_in[16];
    hp.cb2    = (const float*)d_in[17];
    hp.cw3    = (const float*)d_in[18];
    hp.cb3    = (const float*)d_in[19];
    hp.S      = (u16*)(ws + 0);            // 786432
    hp.recip  = (float*)(ws + 786432);     // 6144
    hp.Acat1  = (u16*)(ws + 792576);       // 2752512
    hp.Acat2  = (u16*)(ws + 3545088);      // 2752512
    hp.Pemb   = (u16*)(ws + 6297600);      // 393216
    hp.Px     = (u16*)(ws + 6690816);      // 393216
    hp.PW1    = (u16*)(ws + 7084032);      // 8257536
    hp.PC1    = (u16*)(ws + 15341568);     // 491520
    hp.Pw2c   = (u16*)(ws + 15833088);     // 102400
    hp.Pw3    = (u16*)(ws + 15935488);     // 10240
    hp.W2C1p  = (u16*)(ws + 15945728);     // 3440640
    hp.cvec   = (float*)(ws + 19386368);   // 1280
    hp.AB     = (float*)(ws + 19387648);   // 327680
    hp.outp   = (float*)d_out;

    kp0<<<2406, 256, 0, stream>>>(hp);   // setup: S/recip, packs, embed tail
    kp1<<<1367, 256, 0, stream>>>(hp);   // mean1 (4608) + W2C1 (840) + cvec (20)
    kp2<<<768, 256, 0, stream>>>(hp);    // conv1 (+relu, + packed Px)
    kp3<<<1152, 256, 0, stream>>>(hp);   // mean2
    kp4<<<320, 256, 0, stream>>>(hp);    // AB = Acat2 @ W2C1 + cvec
    kp5<<<1020, 256, 0, stream>>>(hp);   // fused pair MLP
}

// Round 10
// 91.208 us; speedup vs baseline: 5.3514x; 1.1304x over previous
//
#include <hip/hip_runtime.h>

typedef unsigned short u16;
typedef unsigned int   u32;
typedef __attribute__((ext_vector_type(8))) short bf16x8;   // 8 bf16 in 4 VGPRs
typedef __attribute__((ext_vector_type(4))) float f32x4;

#define KCAT 5376   // 6*768 (mean) + 768 (root)

struct Params {
    const float* embed; const int* labels;
    const float* c1w; const float* c1root; const float* c1b;
    const float* c2w; const float* c2root; const float* c2b;
    const float* cw1; const float* cb1; const float* cw2;
    const float* cb2; const float* cw3; const float* cb3;
    u16* S; float* recip; u16* Acat1; u16* Acat2;
    u16* Pemb; u16* Px; u16* PW1; u16* PC1; u16* Pw2c; u16* Pw3;
    u16* W2C1p; float* cvec; float* AB; float* outp;
};

__device__ inline u16 f2bf(float f) {
    union { float f; u32 u; } v; v.f = f;
    u32 r = v.u + 0x7FFFu + ((v.u >> 16) & 1u);   // RNE
    return (u16)(r >> 16);
}
__device__ inline f32x4 mfma16(bf16x8 a, bf16x8 b, f32x4 c) {
    return __builtin_amdgcn_mfma_f32_16x16x32_bf16(a, b, c, 0, 0, 0);
}

// pack one 32x16 tile of a row-major f32 matrix into MFMA B-fragment layout (bf16)
__device__ inline void pack_f32(const float* __restrict__ src, int ld, int rows, int cols,
                                u16* __restrict__ dst, int ntot, int kt0, int nt0,
                                int ntiles, int tile) {
    int ktile = tile / ntiles, ntile = tile % ntiles;
    int lane = threadIdx.x & 63;
    int m = lane & 15, hi = lane >> 4;
    int n = ntile * 16 + m;
    u16 tmp[8];
#pragma unroll
    for (int j = 0; j < 8; ++j) {
        int kk = ktile * 32 + hi * 8 + j;
        tmp[j] = (kk < rows && n < cols) ? f2bf(src[(size_t)kk * ld + n]) : (u16)0;
    }
    u16* d = dst + (((size_t)(kt0 + ktile) * ntot + (nt0 + ntile)) * 64 + lane) * 8;
    *(bf16x8*)d = *(const bf16x8*)tmp;
}

// one-wave 16x16 GEMM tile, A row-major bf16, B pre-packed
__device__ inline f32x4 gemm_tile(const u16* __restrict__ A, int lda,
                                  const u16* __restrict__ Bp,
                                  int row0, int nt, int ntot, int ktiles) {
    int lane = threadIdx.x & 63;
    int m = lane & 15, hi = lane >> 4;
    const u16* arow = A + (size_t)(row0 + m) * lda + hi * 8;
    const u16* bptr = Bp + ((size_t)nt * 64 + lane) * 8;
    f32x4 acc = {0.f, 0.f, 0.f, 0.f};
#pragma unroll 4
    for (int kt = 0; kt < ktiles; ++kt) {
        bf16x8 a = *(const bf16x8*)(arow + kt * 32);
        bf16x8 b = *(const bf16x8*)(bptr + (size_t)kt * ntot * 512);
        acc = mfma16(a, b, acc);
    }
    return acc;
}

// ---------------- P0: S/recip + embed tail + all packs ----------------
__global__ __launch_bounds__(256) void kp0(Params p) {
    int w = threadIdx.x >> 6, lane = threadIdx.x & 63;
    int job = blockIdx.x * 4 + w;
    if (job < 256) {
        int k = job;
        int lab[4];
#pragma unroll
        for (int g = 0; g < 4; ++g) {
            int i = lane + g * 64;
            lab[g] = (i == k) ? -1 : p.labels[i * 255 + k - (k > i ? 1 : 0)];
        }
#pragma unroll
        for (int r = 0; r < 6; ++r) {
            int c = 0;
#pragma unroll
            for (int g = 0; g < 4; ++g) c += __popcll(__ballot(lab[g] == r));
#pragma unroll
            for (int g = 0; g < 4; ++g) {
                int i = lane + g * 64;
                p.S[(k * 6 + r) * 256 + i] = (lab[g] == r) ? (u16)0x3F80 : (u16)0;
            }
            if (lane == 0) p.recip[k * 6 + r] = 1.0f / (float)(c > 1 ? c : 1);
        }
    } else if (job < 640) {
        int idx = (job - 256) * 512 + lane * 8;
        int row = idx / 768, col = idx - row * 768;
        f32x4 a = *(const f32x4*)(p.embed + idx);
        f32x4 b = *(const f32x4*)(p.embed + idx + 4);
        u16 tmp[8];
#pragma unroll
        for (int e = 0; e < 4; ++e) { tmp[e] = f2bf(a[e]); tmp[e + 4] = f2bf(b[e]); }
        *(bf16x8*)(p.Acat1 + (size_t)row * KCAT + 4608 + col) = *(const bf16x8*)tmp;
    }
    else if (job < 1024) pack_f32(p.embed, 768, 256, 768, p.Pemb, 48, 0, 0, 48, job - 640);
    else if (job < 7936) pack_f32(p.c1w, 768, 4608, 768, p.PW1, 48, 0, 0, 48, job - 1024);
    else if (job < 9088) pack_f32(p.c1root, 768, 768, 768, p.PW1, 48, 144, 0, 48, job - 7936);
    else if (job < 9328) pack_f32(p.cw1, 150, 768, 150, p.PC1, 20, 0, 0, 10, job - 9088);
    else if (job < 9568) pack_f32(p.cw1 + 768 * 150, 150, 768, 150, p.PC1, 20, 0, 10, 10, job - 9328);
    else if (job < 9618) pack_f32(p.cw2, 150, 150, 150, p.Pw2c, 10, 0, 0, 10, job - 9568);
    else if (job < 9623) pack_f32(p.cw3, 7, 150, 7, p.Pw3, 1, 0, 0, 1, job - 9618);
}

// ---------------- mean tile: (S @ Bp) * recip -> Acat ----------------
__device__ void mean_tile(const Params& p, const u16* Bp, u16* Acat, int tile) {
    int rt = tile / 48, nt = tile % 48;
    f32x4 acc = gemm_tile(p.S, 256, Bp, rt * 16, nt, 48, 8);
    int lane = threadIdx.x & 63;
    int col = nt * 16 + (lane & 15), hi = lane >> 4;
#pragma unroll
    for (int r = 0; r < 4; ++r) {
        int g = rt * 16 + hi * 4 + r;
        float scale = p.recip[g];
        int node = g / 6, rel = g - node * 6;
        Acat[(size_t)node * KCAT + rel * 768 + col] = f2bf(acc[r] * scale);
    }
}

// ---------------- W2C1 = Wcat2 @ C1cat, output packed as B-fragments -----------
// per wave-job: 32 rows x 64 cols (2 m-frags x 4 n-tiles), K=768; 840 jobs total
__device__ void w2c1_job(const Params& p, int q) {
    int lane = threadIdx.x & 63;
    int mtb = q / 5, ntb = q % 5;
    int m = lane & 15, hi = lane >> 4;
    int row0 = mtb * 32;
    f32x4 acc[2][4];
#pragma unroll
    for (int t = 0; t < 2; ++t)
#pragma unroll
        for (int qq = 0; qq < 4; ++qq) acc[t][qq] = {0.f, 0.f, 0.f, 0.f};
    for (int kt = 0; kt < 24; ++kt) {
        int e0 = kt * 32 + hi * 8;
        bf16x8 a[2];
#pragma unroll
        for (int t = 0; t < 2; ++t) {
            int r = row0 + t * 16 + m;
            const float* src = (r < 4608) ? (p.c2w + (size_t)r * 768)
                                          : (p.c2root + (size_t)(r - 4608) * 768);
            f32x4 x0 = *(const f32x4*)(src + e0);
            f32x4 x1 = *(const f32x4*)(src + e0 + 4);
            u16 tmp[8];
#pragma unroll
            for (int e = 0; e < 4; ++e) { tmp[e] = f2bf(x0[e]); tmp[e + 4] = f2bf(x1[e]); }
            a[t] = *(const bf16x8*)tmp;
        }
#pragma unroll
        for (int qq = 0; qq < 4; ++qq) {
            int nt = ntb * 4 + qq;
            bf16x8 b = *(const bf16x8*)(p.PC1 + ((size_t)(kt * 20 + nt) * 64 + lane) * 8);
            acc[0][qq] = mfma16(a[0], b, acc[0][qq]);
            acc[1][qq] = mfma16(a[1], b, acc[1][qq]);
        }
    }
#pragma unroll
    for (int t = 0; t < 2; ++t)
#pragma unroll
        for (int qq = 0; qq < 4; ++qq) {
            int nt = ntb * 4 + qq;
#pragma unroll
            for (int r4 = 0; r4 < 4; ++r4) {
                int kg = row0 + t * 16 + hi * 4 + r4;
                int kt2 = kg >> 5, j = kg & 7, hi2 = (kg >> 3) & 3;
                p.W2C1p[(((size_t)kt2 * 20 + nt) * 64 + hi2 * 16 + m) * 8 + j] = f2bf(acc[t][qq][r4]);
            }
        }
}

// ---------------- cvec via MFMA: cvec = c2b @ C1cat (+ b1 on A-half) -----------
__device__ void cvec_job(const Params& p, int nt) {
    int lane = threadIdx.x & 63;
    int m = lane & 15, hi = lane >> 4;
    f32x4 acc = {0.f, 0.f, 0.f, 0.f};
    for (int kt = 0; kt < 24; ++kt) {
        int e0 = kt * 32 + hi * 8;
        f32x4 x0 = *(const f32x4*)(p.c2b + e0);
        f32x4 x1 = *(const f32x4*)(p.c2b + e0 + 4);
        u16 tmp[8];
#pragma unroll
        for (int e = 0; e < 4; ++e) {
            tmp[e]     = (m == 0) ? f2bf(x0[e]) : (u16)0;
            tmp[e + 4] = (m == 0) ? f2bf(x1[e]) : (u16)0;
        }
        bf16x8 a = *(const bf16x8*)tmp;
        bf16x8 b = *(const bf16x8*)(p.PC1 + ((size_t)(kt * 20 + nt) * 64 + lane) * 8);
        acc = mfma16(a, b, acc);
    }
    if (lane < 16) {                        // D row 0 = lanes 0..15, reg 0
        int j = nt * 16 + lane;
        float bias = (j < 150) ? p.cb1[j] : 0.f;
        p.cvec[j] = acc[0] + bias;
    }
}

// ---------------- P1: mean1 only (4608 jobs) ----------------
__global__ __launch_bounds__(256) void kp1(Params p) {
    int w = threadIdx.x >> 6;
    int job = blockIdx.x * 4 + w;
    if (job < 4608) mean_tile(p, p.Pemb, p.Acat1, job);
}

// ---------------- P2: conv1 (768 blocks) + w2c1 (210 blocks) + cvec (5) --------
__global__ __launch_bounds__(256) void kp2(Params p) {
    __shared__ float red[4 * 64 * 4];
    int w = threadIdx.x >> 6, lane = threadIdx.x & 63;
    int b = blockIdx.x;
    if (b >= 768) {
        int job = (b - 768) * 4 + w;
        if (job < 840)      w2c1_job(p, job);
        else if (job < 860) cvec_job(p, job - 840);
        return;
    }
    int m = lane & 15, hi = lane >> 4;
    int rt = b / 48, nt = b % 48;
    const u16* arow = p.Acat1 + (size_t)(rt * 16 + m) * KCAT + hi * 8;
    const u16* bptr = p.PW1 + ((size_t)nt * 64 + lane) * 8;
    f32x4 acc = {0.f, 0.f, 0.f, 0.f};
#pragma unroll 4
    for (int kt = w * 42; kt < (w + 1) * 42; ++kt) {
        bf16x8 a = *(const bf16x8*)(arow + kt * 32);
        bf16x8 bb = *(const bf16x8*)(bptr + (size_t)kt * 48 * 512);
        acc = mfma16(a, bb, acc);
    }
    *(f32x4*)&red[(w * 64 + lane) * 4] = acc;
    __syncthreads();
    if (w == 0) {
        f32x4 s = *(f32x4*)&red[lane * 4];
#pragma unroll
        for (int ww = 1; ww < 4; ++ww) s += *(f32x4*)&red[(ww * 64 + lane) * 4];
        int col = nt * 16 + m;
        float bbv = p.c1b[col];
#pragma unroll
        for (int r = 0; r < 4; ++r) {
            int g = rt * 16 + hi * 4 + r;
            float v = fmaxf(s[r] + bbv, 0.f);
            u16 bv = f2bf(v);
            p.Acat2[(size_t)g * KCAT + 4608 + col] = bv;
            p.Px[(((size_t)(g >> 5) * 48 + nt) * 64 + (((g >> 3) & 3) * 16 + m)) * 8 + (g & 7)] = bv;
        }
    }
}

// ---------------- P3: mean2 ----------------
__global__ __launch_bounds__(256) void kp3(Params p) {
    int w = threadIdx.x >> 6;
    int job = blockIdx.x * 4 + w;
    if (job < 4608) mean_tile(p, p.Px, p.Acat2, job);
}

// ---------------- P4: AB = Acat2 @ W2C1p + cvec (K split over 4 waves) ---------
__global__ __launch_bounds__(256) void kp4(Params p) {
    __shared__ float red2[4 * 64 * 4];
    int w = threadIdx.x >> 6, lane = threadIdx.x & 63;
    int m = lane & 15, hi = lane >> 4;
    int b = blockIdx.x;
    int rt = b / 20, nt = b % 20;
    const u16* arow = p.Acat2 + (size_t)(rt * 16 + m) * KCAT + hi * 8;
    const u16* bptr = p.W2C1p + ((size_t)nt * 64 + lane) * 8;
    f32x4 acc = {0.f, 0.f, 0.f, 0.f};
#pragma unroll 4
    for (int kt = w * 42; kt < (w + 1) * 42; ++kt) {
        bf16x8 a = *(const bf16x8*)(arow + kt * 32);
        bf16x8 bb = *(const bf16x8*)(bptr + (size_t)kt * 20 * 512);
        acc = mfma16(a, bb, acc);
    }
    *(f32x4*)&red2[(w * 64 + lane) * 4] = acc;
    __syncthreads();
    if (w == 0) {
        f32x4 s = *(f32x4*)&red2[lane * 4];
#pragma unroll
        for (int ww = 1; ww < 4; ++ww) s += *(f32x4*)&red2[(ww * 64 + lane) * 4];
        int j = nt * 16 + m;
        float cv = p.cvec[j];
#pragma unroll
        for (int r = 0; r < 4; ++r) {
            int g = rt * 16 + hi * 4 + r;
            p.AB[(size_t)g * 320 + j] = s[r] + cv;
        }
    }
}

// ---------------- P5: fused pair MLP ----------------
__global__ __launch_bounds__(256) void kp5(Params p) {
    __shared__ u16 h2t[4][16][168];
    int w = threadIdx.x >> 6, lane = threadIdx.x & 63;
    int m = lane & 15, hi = lane >> 4;
    int pb = blockIdx.x * 64 + w * 16;
    int pp = pb + m;
    int i = pp / 255, rem = pp - i * 255;
    int k = rem + (rem >= i ? 1 : 0);
    const float* Ar = p.AB + (size_t)i * 320;
    const float* Br = p.AB + (size_t)k * 320 + 160;

    bf16x8 af[5];
#pragma unroll
    for (int kk = 0; kk < 5; ++kk) {
        int c = kk * 32 + hi * 8;
        f32x4 a0 = *(const f32x4*)(Ar + c);
        f32x4 a1 = *(const f32x4*)(Ar + c + 4);
        f32x4 b0 = *(const f32x4*)(Br + c);
        f32x4 b1v = *(const f32x4*)(Br + c + 4);
        f32x4 s0 = a0 + b0, s1 = a1 + b1v;
        bf16x8 f;
#pragma unroll
        for (int e = 0; e < 4; ++e) {
            f[e]     = (short)f2bf(fmaxf(s0[e], 0.f));
            f[e + 4] = (short)f2bf(fmaxf(s1[e], 0.f));
        }
        af[kk] = f;
    }

#pragma unroll
    for (int nt = 0; nt < 10; ++nt) {
        f32x4 acc = {0.f, 0.f, 0.f, 0.f};
#pragma unroll
        for (int kk = 0; kk < 5; ++kk) {
            bf16x8 b = *(const bf16x8*)(p.Pw2c + ((size_t)(kk * 10 + nt) * 64 + lane) * 8);
            acc = mfma16(af[kk], b, acc);
        }
        int col = nt * 16 + m;
        float bb = (col < 150) ? p.cb2[col] : 0.f;
#pragma unroll
        for (int r = 0; r < 4; ++r) {
            float v = fmaxf(acc[r] + bb, 0.f);
            h2t[w][hi * 4 + r][col] = f2bf(v);
        }
    }
    __syncthreads();

    f32x4 acc3 = {0.f, 0.f, 0.f, 0.f};
#pragma unroll
    for (int kk = 0; kk < 5; ++kk) {
        bf16x8 a = *(const bf16x8*)(&h2t[w][m][kk * 32 + hi * 8]);
        bf16x8 b = *(const bf16x8*)(p.Pw3 + ((size_t)kk * 64 + lane) * 8);
        acc3 = mfma16(a, b, acc3);
    }
    if (m < 7) {
        float bb = p.cb3[m];
#pragma unroll
        for (int r = 0; r < 4; ++r) {
            int p2 = pb + hi * 4 + r;
            p.outp[p2 * 7 + m] = acc3[r] + bb;
        }
    }
}

extern "C" void kernel_launch(void* const* d_in, const int* in_sizes, int n_in,
                              void* d_out, int out_size, void* d_ws, size_t ws_size,
                              hipStream_t stream) {
    char* ws = (char*)d_ws;
    Params hp;
    hp.embed  = (const float*)d_in[0];
    hp.labels = (const int*)d_in[1];
    hp.c1w    = (const float*)d_in[2];
    hp.c1root = (const float*)d_in[3];
    hp.c1b    = (const float*)d_in[4];
    hp.c2w    = (const float*)d_in[5];
    hp.c2root = (const float*)d_in[6];
    hp.c2b    = (const float*)d_in[7];
    // d_in[8..13] (base_*) are dead code
    hp.cw1    = (const float*)d_in[14];
    hp.cb1    = (const float*)d_in[15];
    hp.cw2    = (const float*)d_in[16];
    hp.cb2    = (const float*)d_in[17];
    hp.cw3    = (const float*)d_in[18];
    hp.cb3    = (const float*)d_in[19];
    hp.S      = (u16*)(ws + 0);            // 786432
    hp.recip  = (float*)(ws + 786432);     // 6144
    hp.Acat1  = (u16*)(ws + 792576);       // 2752512
    hp.Acat2  = (u16*)(ws + 3545088);      // 2752512
    hp.Pemb   = (u16*)(ws + 6297600);      // 393216
    hp.Px     = (u16*)(ws + 6690816);      // 393216
    hp.PW1    = (u16*)(ws + 7084032);      // 8257536
    hp.PC1    = (u16*)(ws + 15341568);     // 491520
    hp.Pw2c   = (u16*)(ws + 15833088);     // 102400
    hp.Pw3    = (u16*)(ws + 15935488);     // 10240
    hp.W2C1p  = (u16*)(ws + 15945728);     // 3440640
    hp.cvec   = (float*)(ws + 19386368);   // 1280
    hp.AB     = (float*)(ws + 19387648);   // 327680
    hp.outp   = (float*)d_out;

    kp0<<<2406, 256, 0, stream>>>(hp);   // setup: S/recip, packs, embed tail
    kp1<<<1152, 256, 0, stream>>>(hp);   // mean1 only
    kp2<<<983, 256, 0, stream>>>(hp);    // conv1 + w2c1 + cvec (overlapped)
    kp3<<<1152, 256, 0, stream>>>(hp);   // mean2
    kp4<<<320, 256, 0, stream>>>(hp);    // AB = Acat2 @ W2C1 + cvec
    kp5<<<1020, 256, 0, stream>>>(hp);   // fused pair MLP
}